// Round 6
// baseline (196.225 us; speedup 1.0000x reference)
//
#include <hip/hip_runtime.h>
#include <cfloat>

// Problem constants (fixed by reference): B=4, N=M=8192, D=3, fp32.
#define BB    4
#define NN    8192
#define MM    8192
#define NPTS  (BB * NN)        // 32768 points per tensor
#define QT    8                // queries per thread (register tile)
#define QB    (256 * QT)       // 2048 queries per block
#define QBLKS (NPTS / QB)      // 16 query-blocks per direction
#define CH    32               // target chunks per direction
#define CHUNK (MM / CH)        // 256 targets per chunk
#define GRID_MAIN (2 * QBLKS * CH)   // 1024 blocks

typedef float f32x2 __attribute__((ext_vector_type(2)));

__device__ __forceinline__ f32x2 pk_fma(f32x2 a, f32x2 b, f32x2 c) {
    return __builtin_elementwise_fma(a, b, c);   // llvm.fma.v2f32
}

// Monotone float->uint mapping so uint atomicMin == float min (handles negatives).
__device__ __forceinline__ unsigned int fmap(float f) {
    unsigned int u = __float_as_uint(f);
    return (u & 0x80000000u) ? ~u : (u | 0x80000000u);
}
__device__ __forceinline__ float funmap(unsigned int u) {
    u = (u & 0x80000000u) ? (u & 0x7FFFFFFFu) : ~u;
    return __uint_as_float(u);
}

// Pack target pairs into stream layout (x0,x1,y0,y1,z0,z1,w0,w1), w=||t||^2.
// Also: init mins to +inf (ordered uint) and zero the completion counter.
__global__ void chamfer_prep(const float* __restrict__ gts,
                             const float* __restrict__ preds,
                             float* __restrict__ sg, float* __restrict__ sp,
                             unsigned int* __restrict__ mins,
                             unsigned int* __restrict__ counter) {
    int idx = blockIdx.x * 256 + threadIdx.x;   // 65536 threads
    mins[idx] = 0xFFFFFFFFu;
    if (idx == 0) *counter = 0u;
    if (idx < 2 * (NPTS / 2)) {                 // 32768 pairs total
        int tensor = idx >> 14;                 // 16384 pairs per tensor
        int pr     = idx & 16383;
        const float* src = tensor ? preds : gts;
        float* dst       = tensor ? sp    : sg;
        const float* a = src + (size_t)pr * 6;
        float x0 = a[0], y0 = a[1], z0 = a[2];
        float x1 = a[3], y1 = a[4], z1 = a[5];
        float w0 = fmaf(x0, x0, fmaf(y0, y0, z0 * z0));
        float w1 = fmaf(x1, x1, fmaf(y1, y1, z1 * z1));
        float4* d4 = (float4*)(dst + (size_t)pr * 8);
        d4[0] = make_float4(x0, x1, y0, y1);
        d4[1] = make_float4(z0, z1, w0, w1);
    }
}

// Each thread: QT=8 queries vs CHUNK targets streamed through SGPRs
// (wave-uniform s_load — no LDS, no __syncthreads in the hot loop).
// m = min_j(||t||^2 - 2 q.t); ||q||^2 added in the tail reduction.
// Inner per 2 targets per query: 3 v_pk_fma_f32 + 1 v_min3_f32 (or the
// scalarized 6 fma + 1 min3 fallback — still LDS-free).
// Last block (counter) reduces mins -> out[0].
__global__ void __launch_bounds__(256, 4) chamfer_main(
        const float* __restrict__ gts, const float* __restrict__ preds,
        const float* __restrict__ sg, const float* __restrict__ sp,
        unsigned int* __restrict__ mins, unsigned int* __restrict__ counter,
        float* __restrict__ out) {
    int bid  = blockIdx.x;          // 1024 blocks
    int dir  = bid >> 9;            // 512 per direction
    int bi   = bid & 511;
    int pblk = bi & (QBLKS - 1);    // 16 query-blocks
    int ch   = bi >> 4;             // 32 chunks
    int b    = pblk >> 2;           // batch (QB=2048 -> 4 qblocks/batch)

    const float* __restrict__ Q = dir ? preds : gts;
    const float* __restrict__ S = dir ? sg : sp;     // targets = other tensor
    const f32x2* __restrict__ S2 =
        (const f32x2*)(S + (size_t)(b * MM + ch * CHUNK) * 4);

    int qbase = pblk * QB + threadIdx.x;
    f32x2 nqx[QT], nqy[QT], nqz[QT];
    float m[QT];
    #pragma unroll
    for (int k = 0; k < QT; ++k) {
        const float* qp = Q + (size_t)(qbase + 256 * k) * 3;
        float ax = -2.0f * qp[0], ay = -2.0f * qp[1], az = -2.0f * qp[2];
        nqx[k] = (f32x2){ax, ax};
        nqy[k] = (f32x2){ay, ay};
        nqz[k] = (f32x2){az, az};
        m[k] = FLT_MAX;
    }

    #pragma unroll 4
    for (int p = 0; p < CHUNK / 2; ++p) {
        f32x2 x01 = S2[4 * p + 0];   // uniform -> SGPRs via s_load
        f32x2 y01 = S2[4 * p + 1];
        f32x2 z01 = S2[4 * p + 2];
        f32x2 w01 = S2[4 * p + 3];
        #pragma unroll
        for (int k = 0; k < QT; ++k) {
            f32x2 s = pk_fma(nqz[k], z01, w01);
            s = pk_fma(nqy[k], y01, s);
            s = pk_fma(nqx[k], x01, s);
            m[k] = fminf(m[k], fminf(s.x, s.y));   // v_min3_f32
        }
    }

    #pragma unroll
    for (int k = 0; k < QT; ++k)
        atomicMin(&mins[dir * NPTS + qbase + 256 * k], fmap(m[k]));

    // ---- last-block tail reduction ----
    __threadfence();
    __shared__ bool amLast;
    if (threadIdx.x == 0)
        amLast = (__hip_atomic_fetch_add(counter, 1u, __ATOMIC_ACQ_REL,
                                         __HIP_MEMORY_SCOPE_AGENT)
                  == GRID_MAIN - 1);
    __syncthreads();
    if (!amLast) return;

    float acc = 0.f;
    #pragma unroll 4
    for (int i = threadIdx.x; i < 2 * NPTS; i += 256) {
        unsigned int u = __hip_atomic_load(&mins[i], __ATOMIC_RELAXED,
                                           __HIP_MEMORY_SCOPE_AGENT);
        const float* qp = (i < NPTS) ? (gts + (size_t)i * 3)
                                     : (preds + (size_t)(i - NPTS) * 3);
        float x = qp[0], y = qp[1], z = qp[2];
        acc += funmap(u) + fmaf(x, x, fmaf(y, y, z * z));
    }
    #pragma unroll
    for (int off = 32; off > 0; off >>= 1)
        acc += __shfl_down(acc, off, 64);
    __shared__ float sred[4];
    int lane = threadIdx.x & 63, w = threadIdx.x >> 6;
    if (lane == 0) sred[w] = acc;
    __syncthreads();
    if (threadIdx.x == 0)
        out[0] = sred[0] + sred[1] + sred[2] + sred[3];
}

extern "C" void kernel_launch(void* const* d_in, const int* in_sizes, int n_in,
                              void* d_out, int out_size, void* d_ws, size_t ws_size,
                              hipStream_t stream) {
    const float* gts   = (const float*)d_in[0];
    const float* preds = (const float*)d_in[1];
    float* out = (float*)d_out;

    char* ws = (char*)d_ws;
    float* sg = (float*)ws;                                   // 512 KB
    float* sp = (float*)(ws + (size_t)NPTS * 4 * sizeof(float));   // 512 KB
    unsigned int* mins    = (unsigned int*)(ws + (size_t)2 * NPTS * 4 * sizeof(float)); // 256 KB
    unsigned int* counter = (unsigned int*)(ws + (size_t)2 * NPTS * 4 * sizeof(float)
                                               + (size_t)2 * NPTS * sizeof(unsigned int));

    chamfer_prep<<<(2 * NPTS) / 256, 256, 0, stream>>>(gts, preds, sg, sp, mins, counter);
    chamfer_main<<<GRID_MAIN, 256, 0, stream>>>(gts, preds, sg, sp, mins, counter, out);
}

// Round 7
// 192.069 us; speedup vs baseline: 1.0216x; 1.0216x over previous
//
#include <hip/hip_runtime.h>
#include <cfloat>

// Problem constants (fixed by reference): B=4, N=M=8192, D=3, fp32.
#define BB      4
#define NN      8192
#define NPTS    32768          // points per tensor
#define TBATCH  8192           // targets per batch
#define THALF   4096           // targets per block (2 blocks cover a batch)
#define CHUNK_T 1024           // targets per LDS chunk (32 KB)
#define NCHUNK  (THALF / CHUNK_T)
#define GRID_MAIN 512

typedef _Float16 half8  __attribute__((ext_vector_type(8)));
typedef float    f32x16 __attribute__((ext_vector_type(16)));

__device__ __forceinline__ unsigned pkh(_Float16 a, _Float16 b) {
    unsigned short ua = __builtin_bit_cast(unsigned short, a);
    unsigned short ub = __builtin_bit_cast(unsigned short, b);
    return (unsigned)ua | ((unsigned)ub << 16);
}

// Monotone float->uint map: uint atomicMin == float min.
__device__ __forceinline__ unsigned fmap(float f) {
    unsigned u = __float_as_uint(f);
    return (u & 0x80000000u) ? ~u : (u | 0x80000000u);
}
__device__ __forceinline__ float funmap(unsigned u) {
    u = (u & 0x80000000u) ? (u & 0x7FFFFFFFu) : ~u;
    return __uint_as_float(u);
}

// Target record (32 B in LDS): half0 (k0..7) = (thx,thy,thz,wa, tlx,tly,tlz,wb)
//                              half1 (k8..15)= (thx,thy,thz, 0,0,0,0,0)
// With B = (phx,phy,phz,1, phx,phy,phz,1 | plx,ply,plz,0,...), p = -2q:
// D = th.ph + tl.ph + th.pl + wa + wb = w - 2q.t - tl.pl  (error ~1e-6).
__device__ __forceinline__ void mkrec(float x, float y, float z,
                                      uint4& r0, uint4& r1) {
    float w = fmaf(x, x, fmaf(y, y, z * z));
    _Float16 hx = (_Float16)x, hy = (_Float16)y, hz = (_Float16)z, hw = (_Float16)w;
    _Float16 lx = (_Float16)(x - (float)hx), ly = (_Float16)(y - (float)hy);
    _Float16 lz = (_Float16)(z - (float)hz), lw = (_Float16)(w - (float)hw);
    r0 = (uint4){pkh(hx, hy), pkh(hz, hw), pkh(lx, ly), pkh(lz, lw)};
    r1 = (uint4){pkh(hx, hy), pkh(hz, (_Float16)0.0f), 0u, 0u};
}

// Block: (dir, 256-query block, target-half). 4 waves x 64 queries (2 MFMA
// column-groups of 32). Targets staged+fp16-packed into LDS in chunks; each
// A-read (ds_read_b128, lane*16 contiguous) feeds 2 mfmas (query-group reuse).
// m = per-query running min of (w - 2q.t); ||q||^2 added in the tail.
__global__ void __launch_bounds__(256, 2) chamfer_main(
        const float* __restrict__ gts, const float* __restrict__ preds,
        unsigned* __restrict__ mins, unsigned* __restrict__ counter,
        float* __restrict__ out) {
    __shared__ uint4 sT[CHUNK_T * 2];   // 32 KB: per g-block of 32 targets:
                                        // 32 x half0 (512B) then 32 x half1

    int blk   = blockIdx.x;            // 512 = 2 dir x 128 qblk x 2 thalf
    int dir   = blk >> 8;
    int rest  = blk & 255;
    int qblk  = rest >> 1;             // 128 query blocks of 256
    int thalf = rest & 1;
    int b     = qblk >> 5;             // batch (32 qblks per batch)

    const float* __restrict__ Qraw = dir ? preds : gts;
    const float* __restrict__ Traw = dir ? gts : preds;
    const float* __restrict__ tsrc = Traw + (size_t)(b * TBATCH + thalf * THALF) * 3;

    int tid = threadIdx.x, lane = tid & 63, wv = tid >> 6;
    int col = lane & 31;

    // B-fragments: 2 query groups of 32.
    int qbase = qblk * 256 + wv * 64;
    half8 Bf[2];
    #pragma unroll
    for (int g = 0; g < 2; ++g) {
        const float* qp = Qraw + (size_t)(qbase + g * 32 + col) * 3;
        float px = -2.0f * qp[0], py = -2.0f * qp[1], pz = -2.0f * qp[2];
        _Float16 p0 = (_Float16)px, p1 = (_Float16)py, p2 = (_Float16)pz;
        _Float16 l0 = (_Float16)(px - (float)p0);
        _Float16 l1 = (_Float16)(py - (float)p1);
        _Float16 l2 = (_Float16)(pz - (float)p2);
        half8 Bhi, Blo;
        Bhi[0] = p0; Bhi[1] = p1; Bhi[2] = p2; Bhi[3] = (_Float16)1.0f;
        Bhi[4] = p0; Bhi[5] = p1; Bhi[6] = p2; Bhi[7] = (_Float16)1.0f;
        Blo[0] = l0; Blo[1] = l1; Blo[2] = l2; Blo[3] = (_Float16)0.0f;
        Blo[4] = (_Float16)0.0f; Blo[5] = (_Float16)0.0f;
        Blo[6] = (_Float16)0.0f; Blo[7] = (_Float16)0.0f;
        Bf[g] = (lane < 32) ? Bhi : Blo;   // lane half selects k0..7 / k8..15
    }

    f32x16 zero = {0,0,0,0,0,0,0,0,0,0,0,0,0,0,0,0};
    float m0 = FLT_MAX, m1 = FLT_MAX;
    const char* sb = (const char*)sT;
    int aoff = lane * 16;               // contiguous b128 within each g-block

    for (int c = 0; c < NCHUNK; ++c) {
        // Stage+pack 1024 targets: thread reads 4 contiguous targets (3xfloat4).
        const float4* gsrc = (const float4*)tsrc + (size_t)c * 768 + (size_t)tid * 3;
        float4 f0 = gsrc[0], f1 = gsrc[1], f2 = gsrc[2];
        float tx[4] = {f0.x, f0.w, f1.z, f2.y};
        float ty[4] = {f0.y, f1.x, f1.w, f2.z};
        float tz[4] = {f0.z, f1.y, f2.x, f2.w};
        #pragma unroll
        for (int k = 0; k < 4; ++k) {
            uint4 r0, r1;
            mkrec(tx[k], ty[k], tz[k], r0, r1);
            int r = tid * 4 + k;        // chunk-local target index
            char* d0 = (char*)sT + (r >> 5) * 1024 + (r & 31) * 16;
            *(uint4*)d0 = r0;
            *(uint4*)(d0 + 512) = r1;
        }
        __syncthreads();

        #pragma unroll 4
        for (int g = 0; g < 32; ++g) {
            half8 A = *(const half8*)(sb + g * 1024 + aoff);
            f32x16 d0 = __builtin_amdgcn_mfma_f32_32x32x16_f16(A, Bf[0], zero, 0, 0, 0);
            f32x16 d1 = __builtin_amdgcn_mfma_f32_32x32x16_f16(A, Bf[1], zero, 0, 0, 0);
            #pragma unroll
            for (int i = 0; i < 8; ++i) {
                m0 = fminf(m0, fminf(d0[2 * i], d0[2 * i + 1]));   // v_min3
                m1 = fminf(m1, fminf(d1[2 * i], d1[2 * i + 1]));
            }
        }
        __syncthreads();
    }

    // Each lane-half holds min over half the target rows -> combine.
    m0 = fminf(m0, __shfl_xor(m0, 32, 64));
    m1 = fminf(m1, __shfl_xor(m1, 32, 64));
    if (lane < 32) {
        atomicMin(&mins[dir * NPTS + qbase + col],      fmap(m0));
        atomicMin(&mins[dir * NPTS + qbase + 32 + col], fmap(m1));
    }

    // ---- last-block tail: sum(min + ||q||^2) -> out[0] ----
    __threadfence();
    __shared__ bool amLast;
    if (tid == 0)
        amLast = (__hip_atomic_fetch_add(counter, 1u, __ATOMIC_ACQ_REL,
                                         __HIP_MEMORY_SCOPE_AGENT)
                  == GRID_MAIN - 1);
    __syncthreads();
    if (!amLast) return;

    float acc = 0.f;
    for (int i = tid; i < 2 * NPTS; i += 256) {
        unsigned u = __hip_atomic_load(&mins[i], __ATOMIC_RELAXED,
                                       __HIP_MEMORY_SCOPE_AGENT);
        const float* qp = (i < NPTS) ? (gts + (size_t)i * 3)
                                     : (preds + (size_t)(i - NPTS) * 3);
        float x = qp[0], y = qp[1], z = qp[2];
        acc += funmap(u) + fmaf(x, x, fmaf(y, y, z * z));
    }
    #pragma unroll
    for (int off = 32; off > 0; off >>= 1)
        acc += __shfl_down(acc, off, 64);
    __shared__ float sred[4];
    if ((tid & 63) == 0) sred[tid >> 6] = acc;
    __syncthreads();
    if (tid == 0) out[0] = sred[0] + sred[1] + sred[2] + sred[3];
}

extern "C" void kernel_launch(void* const* d_in, const int* in_sizes, int n_in,
                              void* d_out, int out_size, void* d_ws, size_t ws_size,
                              hipStream_t stream) {
    const float* gts   = (const float*)d_in[0];
    const float* preds = (const float*)d_in[1];
    float* out = (float*)d_out;

    unsigned* mins    = (unsigned*)d_ws;                       // 256 KB
    unsigned* counter = (unsigned*)((char*)d_ws + (size_t)2 * NPTS * 4);

    hipMemsetAsync(mins, 0xFF, (size_t)2 * NPTS * sizeof(unsigned), stream);
    hipMemsetAsync(counter, 0, sizeof(unsigned), stream);
    chamfer_main<<<GRID_MAIN, 256, 0, stream>>>(gts, preds, mins, counter, out);
}